// Round 9
// baseline (516.823 us; speedup 1.0000x reference)
//
#include <hip/hip_runtime.h>
#include <math.h>

#define LEAKY 0.2f
#define NBMAX 256

typedef __attribute__((ext_vector_type(8))) short short8;   // 8 bf16 (4 VGPRs)
typedef __attribute__((ext_vector_type(4))) float f32x4;    // 4 fp32

__device__ __forceinline__ float leaky02(float z) { return z >= 0.f ? z : LEAKY * z; }
__device__ __forceinline__ unsigned short f2bf(float f) {
  unsigned u = __float_as_uint(f);
  unsigned r = u + 0x7fffu + ((u >> 16) & 1u);   // RNE
  return (unsigned short)(r >> 16);
}
__device__ __forceinline__ float bflo(unsigned u) { return __uint_as_float(u << 16); }
__device__ __forceinline__ float bfhi(unsigned u) { return __uint_as_float(u & 0xffff0000u); }

// ================= bucket-partitioned CSR build (dst-major) =================
// Bucket b = dst>>8. Packed pair = (src<<16)|dst (both < 2^16).

__global__ __launch_bounds__(256) void bktcount_kernel(const int* __restrict__ ei,
                                                       int* __restrict__ bucketCnt,
                                                       int E, int N, int NB) {
  __shared__ int bc[NBMAX];
  for (int i = threadIdx.x; i < NB; i += 256) bc[i] = 0;
  __syncthreads();
  int EP = E + N;
  int chunk = (EP + gridDim.x - 1) / gridDim.x;
  int lo = blockIdx.x * chunk, hi = min(EP, lo + chunk);
  for (int e = lo + threadIdx.x; e < hi; e += 256) {
    int d = (e < E) ? ei[E + e] : (e - E);
    atomicAdd(&bc[d >> 8], 1);
  }
  __syncthreads();
  for (int i = threadIdx.x; i < NB; i += 256)
    if (bc[i]) atomicAdd(&bucketCnt[i], bc[i]);
}

__global__ __launch_bounds__(256) void bktscan_kernel(const int* __restrict__ bucketCnt,
                                                      int* __restrict__ bucketOff,
                                                      int* __restrict__ bucketCur, int NB) {
  int tid = threadIdx.x;
  int lane = tid & 63, wv = tid >> 6;
  int v = (tid < NB) ? bucketCnt[tid] : 0;
  int x = v;
#pragma unroll
  for (int off = 1; off < 64; off <<= 1) {
    int t = __shfl_up(x, off);
    if (lane >= off) x += t;
  }
  __shared__ int ws[4];
  if (lane == 63) ws[wv] = x;
  __syncthreads();
  int woff = 0;
#pragma unroll
  for (int w = 0; w < 4; ++w) if (w < wv) woff += ws[w];
  int incl = x + woff;
  if (tid < NB) {
    bucketOff[tid] = incl - v;
    bucketCur[tid] = incl - v;
  }
  if (tid == NB - 1) bucketOff[NB] = incl;
}

__global__ __launch_bounds__(256) void bktscatter_kernel(const int* __restrict__ ei,
                                                         int* __restrict__ bucketCur,
                                                         unsigned* __restrict__ pairs,
                                                         int E, int N, int NB) {
  __shared__ int bc[NBMAX];
  __shared__ int bbase[NBMAX];
  for (int i = threadIdx.x; i < NB; i += 256) bc[i] = 0;
  __syncthreads();
  int EP = E + N;
  int chunk = (EP + gridDim.x - 1) / gridDim.x;
  int lo = blockIdx.x * chunk, hi = min(EP, lo + chunk);
  for (int e = lo + threadIdx.x; e < hi; e += 256) {
    int d = (e < E) ? ei[E + e] : (e - E);
    atomicAdd(&bc[d >> 8], 1);
  }
  __syncthreads();
  for (int i = threadIdx.x; i < NB; i += 256) {
    int c = bc[i];
    bbase[i] = c ? atomicAdd(&bucketCur[i], c) : 0;
    bc[i] = 0;   // reuse as local cursor
  }
  __syncthreads();
  for (int e = lo + threadIdx.x; e < hi; e += 256) {
    int s, d;
    if (e < E) { s = ei[e]; d = ei[E + e]; } else { s = e - E; d = s; }
    int b = d >> 8;
    int slot = bbase[b] + atomicAdd(&bc[b], 1);
    pairs[slot] = ((unsigned)s << 16) | (unsigned)d;
  }
}

__global__ __launch_bounds__(256) void bktcsr_kernel(const unsigned* __restrict__ pairs,
                                                     const int* __restrict__ bucketOff,
                                                     int* __restrict__ rowptr,
                                                     unsigned short* __restrict__ srcs,
                                                     int N, int NB) {
  int b = blockIdx.x;
  int tid = threadIdx.x;
  __shared__ int cnt[256], loff[256], cur[256];
  cnt[tid] = 0;
  cur[tid] = 0;
  __syncthreads();
  int p0 = bucketOff[b], p1 = bucketOff[b + 1];
  for (int j = p0 + tid; j < p1; j += 256)
    atomicAdd(&cnt[pairs[j] & 255], 1);
  __syncthreads();
  int v = cnt[tid];
  int lane = tid & 63, wv = tid >> 6;
  int x = v;
#pragma unroll
  for (int off = 1; off < 64; off <<= 1) {
    int t = __shfl_up(x, off);
    if (lane >= off) x += t;
  }
  __shared__ int ws[4];
  if (lane == 63) ws[wv] = x;
  __syncthreads();
  int woff = 0;
#pragma unroll
  for (int w = 0; w < 4; ++w) if (w < wv) woff += ws[w];
  int excl = x + woff - v;
  loff[tid] = excl;
  int node = (b << 8) + tid;
  if (node < N) rowptr[node] = p0 + excl;
  if (b == NB - 1 && tid == 255) rowptr[N] = p1;
  __syncthreads();
  for (int j = p0 + tid; j < p1; j += 256) {
    unsigned pr = pairs[j];
    int ln = pr & 255;
    int slot = p0 + loff[ln] + atomicAdd(&cur[ln], 1);
    srcs[slot] = (unsigned short)(pr >> 16);
  }
}

// ---------------- weight convert: Wt[c][k] = bf16(W[k][c]) ----------------
__global__ void convw_kernel(const float* __restrict__ W1, const float* __restrict__ W2,
                             unsigned short* __restrict__ Wt1, unsigned short* __restrict__ Wt2) {
  int idx = blockIdx.x * 256 + threadIdx.x;   // 0..131071
  const float* W;
  unsigned short* Wt;
  if (idx < 65536) { W = W1; Wt = Wt1; } else { W = W2; Wt = Wt2; idx -= 65536; }
  int c = idx >> 8, k = idx & 255;
  Wt[c * 256 + k] = f2bf(W[k * 256 + c]);
}

// ---------------- bf16 MFMA GEMM, 128x256 tile, 8 waves (2m x 4n) ----------------
// HASBN: compute BN scale/shift per block from raw sums, apply + PReLU on A.
// Epilogue: fused attention dots; LDS-staged coalesced uint4 stores.
template <bool BF16A, bool HASBN>
__global__ __launch_bounds__(512) void gemm_kernel(const void* __restrict__ Av,
                                                   const unsigned short* __restrict__ Wt,
                                                   unsigned short* __restrict__ Hout, int M,
                                                   const float* __restrict__ bn_sum,
                                                   const float* __restrict__ bn_ss,
                                                   const float* __restrict__ gamma,
                                                   const float* __restrict__ beta,
                                                   const float* __restrict__ pwp,
                                                   const float* __restrict__ att_s,
                                                   const float* __restrict__ att_d,
                                                   float* __restrict__ as_o,
                                                   float* __restrict__ ad_o) {
  __shared__ unsigned short As[128][40];    // +8 pad
  __shared__ unsigned short Bs[256][40];
  __shared__ unsigned short stg[8][16][64]; // epilogue staging (16KB)
  __shared__ float bscL[256], bshL[256];
  int tid = threadIdx.x;
  int bm = blockIdx.x * 128;
  int l = tid & 63, wv = tid >> 6;
  int wm = wv >> 2, wn = wv & 3;            // 2 x 4 waves; wave tile 64 rows x 64 cols
  int lr = l & 15, lk = l >> 4;
  f32x4 acc[4][4] = {};
  float pws = pwp ? pwp[0] : 0.f;

  if (HASBN) {
    for (int i = tid; i < 256; i += 512) {
      float mu = bn_sum[i] / (float)M;
      float var = bn_ss[i] / (float)M - mu * mu;
      float sc = gamma[i] * rsqrtf(var + 1e-5f);
      bscL[i] = sc;
      bshL[i] = beta[i] - mu * sc;
    }
    __syncthreads();
  }

  for (int k0 = 0; k0 < 256; k0 += 32) {
    {
      int row = tid >> 2, kq = (tid & 3) * 8;
      int gr = bm + row;
      if (BF16A) {
        uint4 u = make_uint4(0, 0, 0, 0);
        if (gr < M) u = *(const uint4*)((const unsigned short*)Av + (size_t)gr * 256 + k0 + kq);
        if (HASBN) {
          float4 sc0 = *(const float4*)&bscL[k0 + kq];
          float4 sh0 = *(const float4*)&bshL[k0 + kq];
          float4 sc1 = *(const float4*)&bscL[k0 + kq + 4];
          float4 sh1 = *(const float4*)&bshL[k0 + kq + 4];
          float v0 = fmaf(bflo(u.x), sc0.x, sh0.x);
          float v1 = fmaf(bfhi(u.x), sc0.y, sh0.y);
          float v2 = fmaf(bflo(u.y), sc0.z, sh0.z);
          float v3 = fmaf(bfhi(u.y), sc0.w, sh0.w);
          float v4 = fmaf(bflo(u.z), sc1.x, sh1.x);
          float v5 = fmaf(bfhi(u.z), sc1.y, sh1.y);
          float v6 = fmaf(bflo(u.w), sc1.z, sh1.z);
          float v7 = fmaf(bfhi(u.w), sc1.w, sh1.w);
          v0 = v0 >= 0.f ? v0 : v0 * pws; v1 = v1 >= 0.f ? v1 : v1 * pws;
          v2 = v2 >= 0.f ? v2 : v2 * pws; v3 = v3 >= 0.f ? v3 : v3 * pws;
          v4 = v4 >= 0.f ? v4 : v4 * pws; v5 = v5 >= 0.f ? v5 : v5 * pws;
          v6 = v6 >= 0.f ? v6 : v6 * pws; v7 = v7 >= 0.f ? v7 : v7 * pws;
          ushort4 o0, o1;
          o0.x = f2bf(v0); o0.y = f2bf(v1); o0.z = f2bf(v2); o0.w = f2bf(v3);
          o1.x = f2bf(v4); o1.y = f2bf(v5); o1.z = f2bf(v6); o1.w = f2bf(v7);
          *(ushort4*)&As[row][kq] = o0;
          *(ushort4*)&As[row][kq + 4] = o1;
        } else {
          *(uint4*)&As[row][kq] = u;
        }
      } else {
        float4 a0 = make_float4(0.f, 0.f, 0.f, 0.f), a1 = a0;
        if (gr < M) {
          a0 = *(const float4*)((const float*)Av + (size_t)gr * 256 + k0 + kq);
          a1 = *(const float4*)((const float*)Av + (size_t)gr * 256 + k0 + kq + 4);
        }
        ushort4 o0, o1;
        o0.x = f2bf(a0.x); o0.y = f2bf(a0.y); o0.z = f2bf(a0.z); o0.w = f2bf(a0.w);
        o1.x = f2bf(a1.x); o1.y = f2bf(a1.y); o1.z = f2bf(a1.z); o1.w = f2bf(a1.w);
        *(ushort4*)&As[row][kq] = o0;
        *(ushort4*)&As[row][kq + 4] = o1;
      }
    }
#pragma unroll
    for (int it = 0; it < 2; ++it) {
      int i = tid + it * 512;
      int c = i >> 2, kq = (i & 3) * 8;
      *(uint4*)&Bs[c][kq] = *(const uint4*)&Wt[(size_t)c * 256 + k0 + kq];
    }
    __syncthreads();
    short8 af[4], bfr[4];
#pragma unroll
    for (int mt = 0; mt < 4; ++mt) af[mt] = *(const short8*)&As[wm * 64 + mt * 16 + lr][lk * 8];
#pragma unroll
    for (int nt = 0; nt < 4; ++nt) bfr[nt] = *(const short8*)&Bs[wn * 64 + nt * 16 + lr][lk * 8];
#pragma unroll
    for (int mt = 0; mt < 4; ++mt)
#pragma unroll
      for (int nt = 0; nt < 4; ++nt)
        acc[mt][nt] = __builtin_amdgcn_mfma_f32_16x16x32_bf16(af[mt], bfr[nt], acc[mt][nt], 0, 0, 0);
    __syncthreads();
  }

  // attention dots from fp32 acc (per-wave, register-only)
  float asv[4], adv[4];
#pragma unroll
  for (int nt = 0; nt < 4; ++nt) {
    int gc = wn * 64 + nt * 16 + lr;
    asv[nt] = att_s[gc];
    adv[nt] = att_d[gc];
  }
#pragma unroll
  for (int mt = 0; mt < 4; ++mt) {
#pragma unroll
    for (int r = 0; r < 4; ++r) {
      int gr = bm + wm * 64 + mt * 16 + lk * 4 + r;
      float ps = acc[mt][0][r] * asv[0] + acc[mt][1][r] * asv[1] +
                 acc[mt][2][r] * asv[2] + acc[mt][3][r] * asv[3];
      float pd = acc[mt][0][r] * adv[0] + acc[mt][1][r] * adv[1] +
                 acc[mt][2][r] * adv[2] + acc[mt][3][r] * adv[3];
#pragma unroll
      for (int off = 1; off < 16; off <<= 1) {
        ps += __shfl_xor(ps, off);
        pd += __shfl_xor(pd, off);
      }
      if (lr == 0 && gr < M) {
        as_o[gr * 4 + wn] = ps;
        ad_o[gr * 4 + wn] = pd;
      }
    }
  }

  // LDS-staged coalesced H stores
#pragma unroll
  for (int mt = 0; mt < 4; ++mt) {
#pragma unroll
    for (int nt = 0; nt < 4; ++nt)
#pragma unroll
      for (int r = 0; r < 4; ++r)
        stg[wv][lk * 4 + r][nt * 16 + lr] = f2bf(acc[mt][nt][r]);
    __syncthreads();
#pragma unroll
    for (int rd = 0; rd < 2; ++rd) {
      int idx = tid + rd * 512;
      int rowslot = idx >> 5, col8 = (idx & 31) * 8;
      int wm2 = rowslot >> 4, rloc = rowslot & 15;
      int wn2 = col8 >> 6, c = col8 & 63;
      int gr = bm + wm2 * 64 + mt * 16 + rloc;
      if (gr < M)
        *(uint4*)&Hout[(size_t)gr * 256 + col8] = *(const uint4*)&stg[wm2 * 4 + wn2][rloc][c];
    }
    __syncthreads();
  }
}

// ---------------- GAT aggregation: wave per node; 4 uint4 loads in flight ----------------
__global__ __launch_bounds__(256) void agg_kernel(const unsigned short* __restrict__ h,
                                                  const float* __restrict__ as_,
                                                  const float* __restrict__ ad_,
                                                  const int* __restrict__ rowptr,
                                                  const unsigned short* __restrict__ srcs,
                                                  const float* __restrict__ bias,
                                                  unsigned short* __restrict__ out_bf,
                                                  float* __restrict__ out_f,
                                                  int N, int concat) {
  int l = threadIdx.x & 63;
  int n = blockIdx.x * 4 + (threadIdx.x >> 6);
  if (n >= N) return;
  int e0 = rowptr[n], e1 = rowptr[n + 1];
  int deg = e1 - e0;
  int hh = l >> 4, le = l & 15;
  float adh = ad_[n * 4 + hh];

  if (deg <= 64) {
    int sidx[4];
    float lg[4];
#pragma unroll
    for (int t = 0; t < 4; ++t) {
      int j = e0 + le + 16 * t;
      if (j < e1) {
        int s = srcs[j];
        sidx[t] = s;
        lg[t] = leaky02(as_[s * 4 + hh] + adh);
      } else {
        sidx[t] = 0;
        lg[t] = -1e30f;
      }
    }
    float mx = fmaxf(fmaxf(lg[0], lg[1]), fmaxf(lg[2], lg[3]));
#pragma unroll
    for (int off = 1; off < 16; off <<= 1) mx = fmaxf(mx, __shfl_xor(mx, off));
    float ex[4];
    float sm = 0.f;
#pragma unroll
    for (int t = 0; t < 4; ++t) {
      ex[t] = (lg[t] > -1e29f) ? __expf(lg[t] - mx) : 0.f;
      sm += ex[t];
    }
#pragma unroll
    for (int off = 1; off < 16; off <<= 1) sm += __shfl_xor(sm, off);
    float inv = 1.f / (sm + 1e-16f);

    int p = l >> 5, m = l & 31;
    int hsel = (m >> 3) << 4;
    float invb = __shfl(inv, hsel);
    float a[8] = {0.f, 0.f, 0.f, 0.f, 0.f, 0.f, 0.f, 0.f};
#pragma unroll
    for (int t = 0; t < 4; ++t) {
      int base = e0 + 16 * t;
      if (base >= e1) break;
      int cntc = min(16, e1 - base);
      int npr = (cntc + 1) >> 1;
      int pr = 0;
      for (; pr + 2 <= npr; pr += 2) {
        int q0 = 2 * pr + p, q1 = q0 + 2;
        int s0 = __shfl(sidx[t], q0);
        float al0 = __shfl(ex[t], q0 + hsel) * invb;
        int s1 = __shfl(sidx[t], q1);
        float al1 = __shfl(ex[t], q1 + hsel) * invb;
        uint4 h0 = *(const uint4*)&h[(size_t)s0 * 256 + m * 8];
        uint4 h1 = *(const uint4*)&h[(size_t)s1 * 256 + m * 8];
        a[0] = fmaf(bflo(h0.x), al0, a[0]); a[1] = fmaf(bfhi(h0.x), al0, a[1]);
        a[2] = fmaf(bflo(h0.y), al0, a[2]); a[3] = fmaf(bfhi(h0.y), al0, a[3]);
        a[4] = fmaf(bflo(h0.z), al0, a[4]); a[5] = fmaf(bfhi(h0.z), al0, a[5]);
        a[6] = fmaf(bflo(h0.w), al0, a[6]); a[7] = fmaf(bfhi(h0.w), al0, a[7]);
        a[0] = fmaf(bflo(h1.x), al1, a[0]); a[1] = fmaf(bfhi(h1.x), al1, a[1]);
        a[2] = fmaf(bflo(h1.y), al1, a[2]); a[3] = fmaf(bfhi(h1.y), al1, a[3]);
        a[4] = fmaf(bflo(h1.z), al1, a[4]); a[5] = fmaf(bfhi(h1.z), al1, a[5]);
        a[6] = fmaf(bflo(h1.w), al1, a[6]); a[7] = fmaf(bfhi(h1.w), al1, a[7]);
      }
      if (pr < npr) {
        int q = 2 * pr + p;
        int s = __shfl(sidx[t], q);
        float al = __shfl(ex[t], q + hsel) * invb;
        uint4 hv = *(const uint4*)&h[(size_t)s * 256 + m * 8];
        a[0] = fmaf(bflo(hv.x), al, a[0]); a[1] = fmaf(bfhi(hv.x), al, a[1]);
        a[2] = fmaf(bflo(hv.y), al, a[2]); a[3] = fmaf(bfhi(hv.y), al, a[3]);
        a[4] = fmaf(bflo(hv.z), al, a[4]); a[5] = fmaf(bfhi(hv.z), al, a[5]);
        a[6] = fmaf(bflo(hv.w), al, a[6]); a[7] = fmaf(bfhi(hv.w), al, a[7]);
      }
    }
#pragma unroll
    for (int i = 0; i < 8; ++i) a[i] += __shfl_xor(a[i], 32);
    if (concat) {
      if (l < 32) {
        float4 b0 = *(const float4*)&bias[m * 8];
        float4 b1 = *(const float4*)&bias[m * 8 + 4];
        ushort4 o0, o1;
        o0.x = f2bf(a[0] + b0.x); o0.y = f2bf(a[1] + b0.y);
        o0.z = f2bf(a[2] + b0.z); o0.w = f2bf(a[3] + b0.w);
        o1.x = f2bf(a[4] + b1.x); o1.y = f2bf(a[5] + b1.y);
        o1.z = f2bf(a[6] + b1.z); o1.w = f2bf(a[7] + b1.w);
        *(ushort4*)&out_bf[(size_t)n * 256 + m * 8] = o0;
        *(ushort4*)&out_bf[(size_t)n * 256 + m * 8 + 4] = o1;
      }
    } else {
#pragma unroll
      for (int i = 0; i < 8; ++i) {
        a[i] += __shfl_xor(a[i], 8);
        a[i] += __shfl_xor(a[i], 16);
      }
      if (l < 8) {
        float4 b0 = *(const float4*)&bias[m * 8];
        float4 b1 = *(const float4*)&bias[m * 8 + 4];
        float4 o0 = make_float4(0.25f * a[0] + b0.x, 0.25f * a[1] + b0.y,
                                0.25f * a[2] + b0.z, 0.25f * a[3] + b0.w);
        float4 o1 = make_float4(0.25f * a[4] + b1.x, 0.25f * a[5] + b1.y,
                                0.25f * a[6] + b1.z, 0.25f * a[7] + b1.w);
        *(float4*)&out_f[(size_t)n * 64 + m * 8] = o0;
        *(float4*)&out_f[(size_t)n * 64 + m * 8 + 4] = o1;
      }
    }
  } else {
    float ad4[4] = {ad_[n * 4], ad_[n * 4 + 1], ad_[n * 4 + 2], ad_[n * 4 + 3]};
    float mx[4] = {-1e30f, -1e30f, -1e30f, -1e30f};
    for (int j = e0 + l; j < e1; j += 64) {
      int s = srcs[j];
      float4 av = *(const float4*)&as_[s * 4];
      mx[0] = fmaxf(mx[0], leaky02(av.x + ad4[0]));
      mx[1] = fmaxf(mx[1], leaky02(av.y + ad4[1]));
      mx[2] = fmaxf(mx[2], leaky02(av.z + ad4[2]));
      mx[3] = fmaxf(mx[3], leaky02(av.w + ad4[3]));
    }
#pragma unroll
    for (int off = 32; off; off >>= 1) {
      mx[0] = fmaxf(mx[0], __shfl_xor(mx[0], off));
      mx[1] = fmaxf(mx[1], __shfl_xor(mx[1], off));
      mx[2] = fmaxf(mx[2], __shfl_xor(mx[2], off));
      mx[3] = fmaxf(mx[3], __shfl_xor(mx[3], off));
    }
    float sm[4] = {0.f, 0.f, 0.f, 0.f};
    for (int j = e0 + l; j < e1; j += 64) {
      int s = srcs[j];
      float4 av = *(const float4*)&as_[s * 4];
      sm[0] += __expf(leaky02(av.x + ad4[0]) - mx[0]);
      sm[1] += __expf(leaky02(av.y + ad4[1]) - mx[1]);
      sm[2] += __expf(leaky02(av.z + ad4[2]) - mx[2]);
      sm[3] += __expf(leaky02(av.w + ad4[3]) - mx[3]);
    }
#pragma unroll
    for (int off = 32; off; off >>= 1) {
      sm[0] += __shfl_xor(sm[0], off);
      sm[1] += __shfl_xor(sm[1], off);
      sm[2] += __shfl_xor(sm[2], off);
      sm[3] += __shfl_xor(sm[3], off);
    }
    float mh = hh == 0 ? mx[0] : hh == 1 ? mx[1] : hh == 2 ? mx[2] : mx[3];
    float sh = hh == 0 ? sm[0] : hh == 1 ? sm[1] : hh == 2 ? sm[2] : sm[3];
    float inv = 1.f / (sh + 1e-16f);
    float a0 = 0.f, a1 = 0.f, a2 = 0.f, a3 = 0.f;
    for (int j = e0; j < e1; ++j) {
      int s = srcs[j];
      float al = __expf(leaky02(as_[s * 4 + hh] + adh) - mh) * inv;
      uint2 hv = *(const uint2*)&h[(size_t)s * 256 + l * 4];
      a0 = fmaf(bflo(hv.x), al, a0); a1 = fmaf(bfhi(hv.x), al, a1);
      a2 = fmaf(bflo(hv.y), al, a2); a3 = fmaf(bfhi(hv.y), al, a3);
    }
    if (concat) {
      float4 b4 = *(const float4*)&bias[l * 4];
      ushort4 o;
      o.x = f2bf(a0 + b4.x); o.y = f2bf(a1 + b4.y);
      o.z = f2bf(a2 + b4.z); o.w = f2bf(a3 + b4.w);
      *(ushort4*)&out_bf[(size_t)n * 256 + l * 4] = o;
    } else {
      a0 += __shfl_xor(a0, 16); a0 += __shfl_xor(a0, 32);
      a1 += __shfl_xor(a1, 16); a1 += __shfl_xor(a1, 32);
      a2 += __shfl_xor(a2, 16); a2 += __shfl_xor(a2, 32);
      a3 += __shfl_xor(a3, 16); a3 += __shfl_xor(a3, 32);
      if (l < 16) {
        float4 b4 = *(const float4*)&bias[l * 4];
        float4 o = make_float4(0.25f * a0 + b4.x, 0.25f * a1 + b4.y,
                               0.25f * a2 + b4.z, 0.25f * a3 + b4.w);
        *(float4*)&out_f[(size_t)n * 64 + l * 4] = o;
      }
    }
  }
}

// ---------------- BatchNorm stats ----------------
__global__ __launch_bounds__(256) void bnstats_bf16_kernel(const unsigned short* __restrict__ x,
                                                           float* __restrict__ sum,
                                                           float* __restrict__ ss, int N) {
  int tid = threadIdx.x;
  int c = (tid & 127) * 2;
  int r = blockIdx.x * 2 + (tid >> 7);
  int stride = gridDim.x * 2;
  float a0 = 0.f, b0 = 0.f, a1 = 0.f, b1 = 0.f;
  for (; r < N; r += stride) {
    unsigned u = *(const unsigned*)&x[(size_t)r * 256 + c];
    float v0 = bflo(u), v1 = bfhi(u);
    a0 += v0; b0 += v0 * v0;
    a1 += v1; b1 += v1 * v1;
  }
  atomicAdd(&sum[c], a0); atomicAdd(&ss[c], b0);
  atomicAdd(&sum[c + 1], a1); atomicAdd(&ss[c + 1], b1);
}

__global__ __launch_bounds__(256) void bnstats_kernel(const float* __restrict__ x,
                                                      float* __restrict__ sum, float* __restrict__ ss,
                                                      int N, int C) {
  int tid = threadIdx.x;
  int f = tid % C;
  int rpb = 256 / C;
  int r = blockIdx.x * rpb + tid / C;
  int stride = gridDim.x * rpb;
  float a = 0.f, b = 0.f;
  for (; r < N; r += stride) {
    float v = x[(size_t)r * C + f];
    a += v;
    b += v * v;
  }
  atomicAdd(&sum[f], a);
  atomicAdd(&ss[f], b);
}

// ---------------- final FC with BN2 (from raw sums) + ELU fused ----------------
__global__ __launch_bounds__(256) void fc_kernel(const float* __restrict__ x,
                                                 const float* __restrict__ bn_sum,
                                                 const float* __restrict__ bn_ss,
                                                 const float* __restrict__ gamma,
                                                 const float* __restrict__ beta,
                                                 const float* __restrict__ W, const float* __restrict__ b,
                                                 float* __restrict__ out, int N) {
  __shared__ float ws[64 * 86];
  __shared__ float xs[32 * 64];
  __shared__ float scL[64], shL[64];
  int tid = threadIdx.x;
  if (tid < 64) {
    float mu = bn_sum[tid] / (float)N;
    float var = bn_ss[tid] / (float)N - mu * mu;
    float sc = gamma[tid] * rsqrtf(var + 1e-5f);
    scL[tid] = sc;
    shL[tid] = beta[tid] - mu * sc;
  }
  for (int i = tid; i < 64 * 86; i += 256) ws[i] = W[i];
  __syncthreads();
  int n0 = blockIdx.x * 32;
  for (int i = tid; i < 32 * 64; i += 256) {
    int n = n0 + (i >> 6), c = i & 63;
    float v = (n < N) ? x[(size_t)n * 64 + c] : 0.f;
    v = fmaf(v, scL[c], shL[c]);
    xs[i] = v > 0.f ? v : expm1f(v);
  }
  __syncthreads();
  for (int idx = tid; idx < 32 * 86; idx += 256) {
    int nl = idx / 86, o = idx % 86;
    int n = n0 + nl;
    if (n >= N) continue;
    float acc = b[o];
    const float* xr = &xs[nl * 64];
#pragma unroll 8
    for (int k = 0; k < 64; ++k) acc = fmaf(xr[k], ws[k * 86 + o], acc);
    out[(size_t)n * 86 + o] = acc;
  }
}

extern "C" void kernel_launch(void* const* d_in, const int* in_sizes, int n_in,
                              void* d_out, int out_size, void* d_ws, size_t ws_size,
                              hipStream_t stream) {
  const float* x    = (const float*)d_in[0];
  const int*   ei   = (const int*)d_in[1];
  const float* W1   = (const float*)d_in[2];
  const float* asw1 = (const float*)d_in[3];
  const float* adw1 = (const float*)d_in[4];
  const float* b1   = (const float*)d_in[5];
  const float* W2   = (const float*)d_in[6];
  const float* asw2 = (const float*)d_in[7];
  const float* adw2 = (const float*)d_in[8];
  const float* b2   = (const float*)d_in[9];
  const float* g1   = (const float*)d_in[10];
  const float* be1  = (const float*)d_in[11];
  const float* g2   = (const float*)d_in[12];
  const float* be2  = (const float*)d_in[13];
  const float* pw   = (const float*)d_in[14];
  const float* fcW  = (const float*)d_in[15];
  const float* fcb  = (const float*)d_in[16];

  const int N = in_sizes[0] / 256;
  const int E = in_sizes[1] / 2;
  const int EP = E + N;
  const int NB = (N + 255) / 256;

  char* ws = (char*)d_ws;
  size_t off = 0;
  auto alloc = [&](size_t bytes) {
    char* p = ws + off;
    off += (bytes + 255) & ~(size_t)255;
    return p;
  };
  unsigned short* h    = (unsigned short*)alloc((size_t)N * 256 * 2);  // bf16 hidden
  unsigned short* outb = (unsigned short*)alloc((size_t)N * 256 * 2);  // bf16 layer-1 out
  float* xm   = (float*)alloc((size_t)N * 64 * 4);                     // fp32 layer-2 out (mean)
  float* as1  = (float*)alloc((size_t)N * 4 * 4);
  float* ad1  = (float*)alloc((size_t)N * 4 * 4);
  float* as2  = (float*)alloc((size_t)N * 4 * 4);
  float* ad2  = (float*)alloc((size_t)N * 4 * 4);
  int* rowptr = (int*)alloc((size_t)(N + 1) * 4);
  unsigned short* srcs = (unsigned short*)alloc((size_t)EP * 2);
  unsigned* pairs = (unsigned*)alloc((size_t)EP * 4);
  int* bucketCnt = (int*)alloc((NBMAX + 1) * 4);
  int* bucketOff = (int*)alloc((NBMAX + 1) * 4);
  int* bucketCur = (int*)alloc((NBMAX + 1) * 4);
  unsigned short* Wt1 = (unsigned short*)alloc(65536 * 2);
  unsigned short* Wt2 = (unsigned short*)alloc(65536 * 2);
  float* bstat = (float*)alloc(512 * 4);
  float* bsum = bstat, *bss = bstat + 256;

  int ngrid4 = (N + 3) / 4;
  int ggrid = (N + 127) / 128;

  // CSR build (bucket-partitioned) + weight conversion
  hipMemsetAsync(bucketCnt, 0, (NBMAX + 1) * 4, stream);
  bktcount_kernel<<<256, 256, 0, stream>>>(ei, bucketCnt, E, N, NB);
  convw_kernel<<<512, 256, 0, stream>>>(W1, W2, Wt1, Wt2);
  bktscan_kernel<<<1, 256, 0, stream>>>(bucketCnt, bucketOff, bucketCur, NB);
  bktscatter_kernel<<<256, 256, 0, stream>>>(ei, bucketCur, pairs, E, N, NB);
  bktcsr_kernel<<<NB, 256, 0, stream>>>(pairs, bucketOff, rowptr, srcs, N, NB);

  // ---- layer 1 (fp32 A converted in-staging) ----
  gemm_kernel<false, false><<<ggrid, 512, 0, stream>>>(x, Wt1, h, N,
                                                       nullptr, nullptr, nullptr, nullptr, nullptr,
                                                       asw1, adw1, as1, ad1);
  agg_kernel<<<ngrid4, 256, 0, stream>>>(h, as1, ad1, rowptr, srcs, b1, outb, nullptr, N, 1);

  hipMemsetAsync(bstat, 0, 512 * 4, stream);
  bnstats_bf16_kernel<<<512, 256, 0, stream>>>(outb, bsum, bss, N);

  // ---- layer 2 (BN1 finalize + apply + PReLU fused into GEMM2 A-staging) ----
  gemm_kernel<true, true><<<ggrid, 512, 0, stream>>>(outb, Wt2, h, N,
                                                     bsum, bss, g1, be1, pw,
                                                     asw2, adw2, as2, ad2);
  agg_kernel<<<ngrid4, 256, 0, stream>>>(h, as2, ad2, rowptr, srcs, b2, nullptr, xm, N, 0);

  hipMemsetAsync(bstat, 0, 128 * 4, stream);
  bnstats_kernel<<<512, 256, 0, stream>>>(xm, bstat, bstat + 64, N, 64);

  // ---- final FC (BN2 finalize + apply + ELU fused) ----
  fc_kernel<<<(N + 31) / 32, 256, 0, stream>>>(xm, bstat, bstat + 64, g2, be2,
                                               fcW, fcb, (float*)d_out, N);
}